// Round 1
// baseline (15730.045 us; speedup 1.0000x reference)
//
#include <hip/hip_runtime.h>

// LSTMForecaster: B=4096, T=512, D=1, H=64, 2 layers + FC(64->1).
// R1: fp32 baseline sharing the skeleton of the planned bf16x3-MFMA kernel.
//   grid 256 blocks x 256 threads, NB=16 batch/block, 1 block/CU.
//   thread = gate row g (0..255); weights for its 3 rows (W_hh0|W_ih1|W_hh1)
//   live in 192 VGPRs; h state in LDS, read as wave-uniform float4 broadcasts.
//   4 barriers/step: L0-gates | update0 | L1-gates | update1.
// Update ownership (matches future MFMA frag-local update): wave w = tid>>6
//   owns unit u = tid&63 for batches [4w, 4w+4); c-state stays in VGPRs.

#define TT 512
#define HH 64
#define NB 16
#define HP 20   // hbuf row pad (floats); 80 B rows keep float4 16B-aligned
#define PP 20   // pre row pad (floats)

__device__ __forceinline__ float sigm_f(float v) {
    return 1.0f / (1.0f + __expf(-v));
}
__device__ __forceinline__ float tanh_f(float v) {
    // 1 - 2/(1+exp(2v)): monotone-safe at both tails (exp->0 gives -1, exp->inf gives 1)
    return 1.0f - 2.0f / (1.0f + __expf(2.0f * v));
}

// 16 FMAs against one weight scalar, h row read as 4 wave-uniform float4s.
#define ACC16(ROWPTR, WK) do { \
    const float4 ha = *(const float4*)((ROWPTR));      \
    const float4 hb = *(const float4*)((ROWPTR) + 4);  \
    const float4 hc = *(const float4*)((ROWPTR) + 8);  \
    const float4 hd = *(const float4*)((ROWPTR) + 12); \
    const float wk_ = (WK); \
    acc[0]  = fmaf(ha.x, wk_, acc[0]);  acc[1]  = fmaf(ha.y, wk_, acc[1]);  \
    acc[2]  = fmaf(ha.z, wk_, acc[2]);  acc[3]  = fmaf(ha.w, wk_, acc[3]);  \
    acc[4]  = fmaf(hb.x, wk_, acc[4]);  acc[5]  = fmaf(hb.y, wk_, acc[5]);  \
    acc[6]  = fmaf(hb.z, wk_, acc[6]);  acc[7]  = fmaf(hb.w, wk_, acc[7]);  \
    acc[8]  = fmaf(hc.x, wk_, acc[8]);  acc[9]  = fmaf(hc.y, wk_, acc[9]);  \
    acc[10] = fmaf(hc.z, wk_, acc[10]); acc[11] = fmaf(hc.w, wk_, acc[11]); \
    acc[12] = fmaf(hd.x, wk_, acc[12]); acc[13] = fmaf(hd.y, wk_, acc[13]); \
    acc[14] = fmaf(hd.z, wk_, acc[14]); acc[15] = fmaf(hd.w, wk_, acc[15]); \
} while (0)

__global__ __launch_bounds__(256, 1)
void lstm_fp32_kernel(const float* __restrict__ x,
                      const float* __restrict__ Wih0, const float* __restrict__ Whh0,
                      const float* __restrict__ bih0, const float* __restrict__ bhh0,
                      const float* __restrict__ Wih1, const float* __restrict__ Whh1,
                      const float* __restrict__ bih1, const float* __restrict__ bhh1,
                      const float* __restrict__ Wfc,  const float* __restrict__ bfc,
                      float* __restrict__ out)
{
    __shared__ float xbuf[NB][TT];        // 32 KB
    __shared__ float hbuf[2 * HH][HP];    // 10 KB: k<64 -> h0[k][b], k>=64 -> h1[k-64][b]
    __shared__ float pre[4 * HH][PP];     // 20 KB: gate preactivations [g][b]

    const int tid = threadIdx.x;
    const int g   = tid;                  // gate row 0..255 (i:0-63, f:64-127, g:128-191, o:192-255)
    const int b0  = blockIdx.x * NB;

    // Stage this block's x slice (coalesced along t).
    for (int i = tid; i < NB * TT; i += 256) {
        const int b = i >> 9;             // TT == 512
        const int t = i & (TT - 1);
        xbuf[b][t] = x[(size_t)(b0 + b) * TT + t];
    }
    // h0 = h1 = 0
    for (int i = tid; i < 2 * HH * HP; i += 256) (&hbuf[0][0])[i] = 0.0f;

    // Per-thread weight rows into VGPRs (one-time, L2-cached across blocks).
    float w0[HH], w1[HH], w2[HH];
#pragma unroll
    for (int k = 0; k < HH; ++k) w0[k] = Whh0[g * HH + k];
#pragma unroll
    for (int k = 0; k < HH; ++k) w1[k] = Wih1[g * HH + k];
#pragma unroll
    for (int k = 0; k < HH; ++k) w2[k] = Whh1[g * HH + k];
    const float wx0 = Wih0[g];                    // D == 1
    const float bb0 = bih0[g] + bhh0[g];
    const float bb1 = bih1[g] + bhh1[g];

    // Update-phase ownership: unit uu for 4 batches starting at bw.
    const int uu = tid & 63;
    const int bw = (tid >> 6) * 4;
    float c0[4] = {0.f, 0.f, 0.f, 0.f};
    float c1[4] = {0.f, 0.f, 0.f, 0.f};

    __syncthreads();

    for (int t = 0; t < TT; ++t) {
        float acc[NB];

        // ---- Phase 1: layer-0 gate preactivations (reads hbuf[0..64) = h0(t-1)) ----
#pragma unroll
        for (int b = 0; b < NB; ++b) acc[b] = fmaf(xbuf[b][t], wx0, bb0);
#pragma unroll
        for (int k = 0; k < HH; ++k) ACC16(&hbuf[k][0], w0[k]);
        {
            float4* pr = (float4*)&pre[g][0];
            pr[0] = make_float4(acc[0], acc[1], acc[2], acc[3]);
            pr[1] = make_float4(acc[4], acc[5], acc[6], acc[7]);
            pr[2] = make_float4(acc[8], acc[9], acc[10], acc[11]);
            pr[3] = make_float4(acc[12], acc[13], acc[14], acc[15]);
        }
        __syncthreads();

        // ---- Phase 2: layer-0 update (writes hbuf[0..64)) ----
        {
            float hv[4];
#pragma unroll
            for (int j = 0; j < 4; ++j) {
                const int b = bw + j;
                const float ig = sigm_f(pre[uu][b]);
                const float fg = sigm_f(pre[uu + 64][b]);
                const float gg = tanh_f(pre[uu + 128][b]);
                const float og = sigm_f(pre[uu + 192][b]);
                const float c  = fmaf(fg, c0[j], ig * gg);
                c0[j] = c;
                hv[j] = og * tanh_f(c);
            }
            *(float4*)&hbuf[uu][bw] = make_float4(hv[0], hv[1], hv[2], hv[3]);
        }
        __syncthreads();

        // ---- Phase 3: layer-1 gate preactivations (reads h0(t) and h1(t-1)) ----
#pragma unroll
        for (int b = 0; b < NB; ++b) acc[b] = bb1;
#pragma unroll
        for (int k = 0; k < HH; ++k) ACC16(&hbuf[k][0], w1[k]);        // W_ih1 . h0(t)
#pragma unroll
        for (int k = 0; k < HH; ++k) ACC16(&hbuf[HH + k][0], w2[k]);   // W_hh1 . h1(t-1)
        {
            float4* pr = (float4*)&pre[g][0];
            pr[0] = make_float4(acc[0], acc[1], acc[2], acc[3]);
            pr[1] = make_float4(acc[4], acc[5], acc[6], acc[7]);
            pr[2] = make_float4(acc[8], acc[9], acc[10], acc[11]);
            pr[3] = make_float4(acc[12], acc[13], acc[14], acc[15]);
        }
        __syncthreads();

        // ---- Phase 4: layer-1 update (writes hbuf[64..128)) ----
        {
            float hv[4];
#pragma unroll
            for (int j = 0; j < 4; ++j) {
                const int b = bw + j;
                const float ig = sigm_f(pre[uu][b]);
                const float fg = sigm_f(pre[uu + 64][b]);
                const float gg = tanh_f(pre[uu + 128][b]);
                const float og = sigm_f(pre[uu + 192][b]);
                const float c  = fmaf(fg, c1[j], ig * gg);
                c1[j] = c;
                hv[j] = og * tanh_f(c);
            }
            *(float4*)&hbuf[HH + uu][bw] = make_float4(hv[0], hv[1], hv[2], hv[3]);
        }
        __syncthreads();
    }

    // ---- FC epilogue: out[b] = h1_last[b] . W_fc + b_fc ----
    if (tid < NB) {
        float s = bfc[0];
#pragma unroll
        for (int u = 0; u < HH; ++u) s = fmaf(hbuf[HH + u][tid], Wfc[u], s);
        out[b0 + tid] = s;
    }
}

extern "C" void kernel_launch(void* const* d_in, const int* in_sizes, int n_in,
                              void* d_out, int out_size, void* d_ws, size_t ws_size,
                              hipStream_t stream) {
    const float* x    = (const float*)d_in[0];
    const float* Wih0 = (const float*)d_in[1];
    const float* Whh0 = (const float*)d_in[2];
    const float* bih0 = (const float*)d_in[3];
    const float* bhh0 = (const float*)d_in[4];
    const float* Wih1 = (const float*)d_in[5];
    const float* Whh1 = (const float*)d_in[6];
    const float* bih1 = (const float*)d_in[7];
    const float* bhh1 = (const float*)d_in[8];
    const float* Wfc  = (const float*)d_in[9];
    const float* bfc  = (const float*)d_in[10];

    lstm_fp32_kernel<<<dim3(4096 / NB), dim3(256), 0, stream>>>(
        x, Wih0, Whh0, bih0, bhh0, Wih1, Whh1, bih1, bhh1, Wfc, bfc, (float*)d_out);
}

// Round 2
// 1244.014 us; speedup vs baseline: 12.6446x; 12.6446x over previous
//
#include <hip/hip_runtime.h>

// LSTMForecaster: B=4096, T=512, D=1, H=64, 2 layers + FC(64->1).
// R2: bf16x3-split MFMA kernel. grid 256 x 256 thr (4 waves), NB=16 batch/block.
//   Weights pre-split into bf16 hi/lo A-fragments (192 regs -> AGPR-eligible as
//   MFMA operands; R1 showed plain-fp32 weights spill at the 256-VGPR VALU cap).
//   h state in LDS as [b][k] bf16 hi/lo planes -> B-frags are ds_read_b128.
//   gates = Whi*hhi + Whi*hlo + Wlo*hhi (drop Wlo*hlo, ~2^-18 rel error).
//   Wave w owns units [16w,16w+16): its 4 M-tiles are gates i/f/g/o for those
//   units -> activation/update is fully register-local (C-frag layout:
//   col=lane&15=batch, row=quad*4+reg=unit-within-16).
//   3 barriers/step: (1) all LDS reads done -> write h0(t); (2) h0(t) visible
//   -> read L1 input frags; (3) h1(t) visible for next step.

#define TT 512
#define HH 64
#define NB 16
#define XP 516    // xbuf pitch (floats): 16B-aligned rows, banks (4b+t)%32 -> <=2-way
#define HTP 136   // ht pitch (bf16): 272B rows, 16B-aligned, <=2-way banks

typedef __bf16 bf16_t;
typedef bf16_t bf16x8 __attribute__((ext_vector_type(8)));
typedef float  f32x4  __attribute__((ext_vector_type(4)));
typedef unsigned short us4 __attribute__((ext_vector_type(4)));

#define MFMA(A, B, C) __builtin_amdgcn_mfma_f32_16x16x32_bf16((A), (B), (C), 0, 0, 0)

__device__ __forceinline__ unsigned short f32_to_bf16_bits(float f) {
    unsigned int u = __builtin_bit_cast(unsigned int, f);
    unsigned int r = u + 0x7fffu + ((u >> 16) & 1u);   // RNE
    return (unsigned short)(r >> 16);
}
__device__ __forceinline__ float bf16bits_to_f32(unsigned short s) {
    unsigned int u = ((unsigned int)s) << 16;
    return __builtin_bit_cast(float, u);
}
__device__ __forceinline__ void split_bf16(float f, unsigned short& hi, unsigned short& lo) {
    hi = f32_to_bf16_bits(f);
    lo = f32_to_bf16_bits(f - bf16bits_to_f32(hi));
}
__device__ __forceinline__ bf16_t bits_to_bf16(unsigned short u) {
    return __builtin_bit_cast(bf16_t, u);
}

// Build hi/lo bf16x8 A-fragments from 8 consecutive fp32 weights.
__device__ __forceinline__ void build_frags(const float* __restrict__ p, bf16x8& hi, bf16x8& lo) {
    const float4 a = *(const float4*)p;
    const float4 b = *(const float4*)(p + 4);
    float v[8] = {a.x, a.y, a.z, a.w, b.x, b.y, b.z, b.w};
#pragma unroll
    for (int j = 0; j < 8; ++j) {
        unsigned short h, l;
        split_bf16(v[j], h, l);
        hi[j] = bits_to_bf16(h);
        lo[j] = bits_to_bf16(l);
    }
}

__device__ __forceinline__ float sigm_f(float v) {
    return 1.0f / (1.0f + __expf(-v));
}
__device__ __forceinline__ float tanh_f(float v) {
    return 1.0f - 2.0f / (1.0f + __expf(2.0f * v));   // tail-safe
}

__global__ __launch_bounds__(256, 1)
void lstm_mfma_kernel(const float* __restrict__ x,
                      const float* __restrict__ Wih0, const float* __restrict__ Whh0,
                      const float* __restrict__ bih0, const float* __restrict__ bhh0,
                      const float* __restrict__ Wih1, const float* __restrict__ Whh1,
                      const float* __restrict__ bih1, const float* __restrict__ bhh1,
                      const float* __restrict__ Wfc,  const float* __restrict__ bfc,
                      float* __restrict__ out)
{
    __shared__ float xbuf[NB][XP];                // ~33 KB
    __shared__ unsigned short ht_hi[NB][HTP];     // 4.25 KB: [b][k], k<64 h0, k>=64 h1
    __shared__ unsigned short ht_lo[NB][HTP];     // 4.25 KB
    __shared__ float h1f[HH][NB + 1];             // 4.25 KB: exact fp32 h1(T-1), [u][b]

    const int tid  = threadIdx.x;
    const int w    = tid >> 6;       // wave 0..3 -> owns units [16w, 16w+16)
    const int lane = tid & 63;
    const int m    = lane & 15;      // A-frag row-in-tile / B-frag & C-frag batch col
    const int q    = lane >> 4;      // quad: A/B k-block, C row-group
    const int b0   = blockIdx.x * NB;

    // ---- Stage x (coalesced float4) ----
    for (int i = tid; i < NB * TT / 4; i += 256) {
        const int b  = i >> 7;            // TT/4 = 128
        const int t4 = i & 127;
        const float4 v = *(const float4*)&x[(size_t)(b0 + b) * TT + t4 * 4];
        *(float4*)&xbuf[b][t4 * 4] = v;
    }
    // ---- h0 = h1 = 0 ----
    for (int i = tid; i < NB * HTP; i += 256) {
        (&ht_hi[0][0])[i] = 0;
        (&ht_lo[0][0])[i] = 0;
    }

    // ---- Weight A-fragments (hi/lo bf16 split), 48 frags = 192 regs ----
    // A[m][k]: m = lane&15 (global row = 64G + 16w + m), k = kt*32 + q*8 + j.
    bf16x8 A0h[4][2], A0l[4][2];     // [gate][ktile] over Whh0 (K=64)
    bf16x8 A1h[4][4], A1l[4][4];     // [gate][ktile] over [Wih1 | Whh1] (K=128)
#pragma unroll
    for (int G = 0; G < 4; ++G) {
        const int row = 64 * G + 16 * w + m;
#pragma unroll
        for (int kt = 0; kt < 2; ++kt)
            build_frags(&Whh0[row * HH + kt * 32 + q * 8], A0h[G][kt], A0l[G][kt]);
#pragma unroll
        for (int kt = 0; kt < 2; ++kt)
            build_frags(&Wih1[row * HH + kt * 32 + q * 8], A1h[G][kt], A1l[G][kt]);
#pragma unroll
        for (int kt = 0; kt < 2; ++kt)
            build_frags(&Whh1[row * HH + kt * 32 + q * 8], A1h[G][2 + kt], A1l[G][2 + kt]);
    }

    // ---- Per-lane bias / Wih0 for C-frag rows: unit u = 16w + q*4 + r ----
    f32x4 bb0v[4], wxv[4], bb1v[4];
#pragma unroll
    for (int G = 0; G < 4; ++G) {
#pragma unroll
        for (int r = 0; r < 4; ++r) {
            const int row = 64 * G + 16 * w + q * 4 + r;
            bb0v[G][r] = bih0[row] + bhh0[row];
            wxv[G][r]  = Wih0[row];             // D == 1
            bb1v[G][r] = bih1[row] + bhh1[row];
        }
    }

    f32x4 c0 = {0.f, 0.f, 0.f, 0.f};
    f32x4 c1 = {0.f, 0.f, 0.f, 0.f};
    const int bcol = m;
    const int u0   = 16 * w + q * 4;

    __syncthreads();

#pragma unroll 1
    for (int t = 0; t < TT; ++t) {
        // ---- Phase 1: all B-frag reads of state (t-1) ----
        bf16x8 h0h[2], h0l[2], h1h[2], h1l[2];
#pragma unroll
        for (int kt = 0; kt < 2; ++kt) {
            h0h[kt] = *(const bf16x8*)&ht_hi[bcol][kt * 32 + q * 8];
            h0l[kt] = *(const bf16x8*)&ht_lo[bcol][kt * 32 + q * 8];
            h1h[kt] = *(const bf16x8*)&ht_hi[bcol][64 + kt * 32 + q * 8];
            h1l[kt] = *(const bf16x8*)&ht_lo[bcol][64 + kt * 32 + q * 8];
        }
        const float xv = xbuf[bcol][t];

        // ---- Phase 2a: L0 gates (24 MFMA) ----
        f32x4 a0[4], a1[4];
#pragma unroll
        for (int G = 0; G < 4; ++G) {
#pragma unroll
            for (int r = 0; r < 4; ++r) a0[G][r] = fmaf(xv, wxv[G][r], bb0v[G][r]);
#pragma unroll
            for (int kt = 0; kt < 2; ++kt) {
                a0[G] = MFMA(A0h[G][kt], h0h[kt], a0[G]);
                a0[G] = MFMA(A0h[G][kt], h0l[kt], a0[G]);
                a0[G] = MFMA(A0l[G][kt], h0h[kt], a0[G]);
            }
        }
        // ---- Phase 2b: L1 partial over h1(t-1) (24 MFMA, hides barrier) ----
#pragma unroll
        for (int G = 0; G < 4; ++G) {
            a1[G] = bb1v[G];
#pragma unroll
            for (int kt = 0; kt < 2; ++kt) {
                a1[G] = MFMA(A1h[G][2 + kt], h1h[kt], a1[G]);
                a1[G] = MFMA(A1h[G][2 + kt], h1l[kt], a1[G]);
                a1[G] = MFMA(A1l[G][2 + kt], h1h[kt], a1[G]);
            }
        }

        // ---- Phase 2c: L0 update (register-local; units u0..u0+3, batch bcol) ----
        us4 ph, pl;
#pragma unroll
        for (int r = 0; r < 4; ++r) {
            const float ig = sigm_f(a0[0][r]);
            const float fg = sigm_f(a0[1][r]);
            const float gg = tanh_f(a0[2][r]);
            const float og = sigm_f(a0[3][r]);
            const float c  = fmaf(fg, c0[r], ig * gg);
            c0[r] = c;
            const float hv = og * tanh_f(c);
            unsigned short hb, lb;
            split_bf16(hv, hb, lb);
            ph[r] = hb;
            pl[r] = lb;
        }
        __syncthreads();                         // (1) all reads of ht(t-1) done
        *(us4*)&ht_hi[bcol][u0] = ph;            // h0(t), 8B aligned
        *(us4*)&ht_lo[bcol][u0] = pl;
        __syncthreads();                         // (2) h0(t) visible

        // ---- Phase 3: L1 over h0(t) (24 MFMA) ----
        bf16x8 g0h[2], g0l[2];
#pragma unroll
        for (int kt = 0; kt < 2; ++kt) {
            g0h[kt] = *(const bf16x8*)&ht_hi[bcol][kt * 32 + q * 8];
            g0l[kt] = *(const bf16x8*)&ht_lo[bcol][kt * 32 + q * 8];
        }
#pragma unroll
        for (int G = 0; G < 4; ++G) {
#pragma unroll
            for (int kt = 0; kt < 2; ++kt) {
                a1[G] = MFMA(A1h[G][kt], g0h[kt], a1[G]);
                a1[G] = MFMA(A1h[G][kt], g0l[kt], a1[G]);
                a1[G] = MFMA(A1l[G][kt], g0h[kt], a1[G]);
            }
        }

        // ---- Phase 4: L1 update ----
#pragma unroll
        for (int r = 0; r < 4; ++r) {
            const float ig = sigm_f(a1[0][r]);
            const float fg = sigm_f(a1[1][r]);
            const float gg = tanh_f(a1[2][r]);
            const float og = sigm_f(a1[3][r]);
            const float c  = fmaf(fg, c1[r], ig * gg);
            c1[r] = c;
            const float hv = og * tanh_f(c);
            unsigned short hb, lb;
            split_bf16(hv, hb, lb);
            ph[r] = hb;
            pl[r] = lb;
            if (t == TT - 1) h1f[u0 + r][bcol] = hv;   // exact fp32 for FC
        }
        // h1(t-1) reads happened pre-barrier(1); all waves are past barrier(2),
        // so writing h1(t) here races with nothing.
        *(us4*)&ht_hi[bcol][64 + u0] = ph;
        *(us4*)&ht_lo[bcol][64 + u0] = pl;
        __syncthreads();                         // (3) h1(t) visible for next step
    }

    // ---- FC epilogue: out[b] = h1_last[b] . Wfc + bfc ----
    if (tid < NB) {
        float s = bfc[0];
#pragma unroll
        for (int u = 0; u < HH; ++u) s = fmaf(h1f[u][tid], Wfc[u], s);
        out[b0 + tid] = s;
    }
}

extern "C" void kernel_launch(void* const* d_in, const int* in_sizes, int n_in,
                              void* d_out, int out_size, void* d_ws, size_t ws_size,
                              hipStream_t stream) {
    const float* x    = (const float*)d_in[0];
    const float* Wih0 = (const float*)d_in[1];
    const float* Whh0 = (const float*)d_in[2];
    const float* bih0 = (const float*)d_in[3];
    const float* bhh0 = (const float*)d_in[4];
    const float* Wih1 = (const float*)d_in[5];
    const float* Whh1 = (const float*)d_in[6];
    const float* bih1 = (const float*)d_in[7];
    const float* bhh1 = (const float*)d_in[8];
    const float* Wfc  = (const float*)d_in[9];
    const float* bfc  = (const float*)d_in[10];

    lstm_mfma_kernel<<<dim3(4096 / NB), dim3(256), 0, stream>>>(
        x, Wih0, Whh0, bih0, bhh0, Wih1, Whh1, bih1, bhh1, Wfc, bfc, (float*)d_out);
}

// Round 3
// 832.428 us; speedup vs baseline: 18.8966x; 1.4944x over previous
//
#include <hip/hip_runtime.h>

// LSTMForecaster: B=4096, T=512, D=1, H=64, 2 layers + FC(64->1).
// R3: layer-pipelined MFMA kernel, ONE barrier per step.
//   - Step t computes L0(t) AND L1(t-1); both read only old-parity LDS state
//     {h0(t-1), h1(t-2)} -> no intra-step dependency, single visibility barrier.
//   - h-state double-buffered (parity = t&1), XOR-swizzled (chunk ^ (m&7),
//     16B chunks, row stride 64 dw == 0 mod 32 -> per-phase 2-way only = free).
//   - Activations use v_rcp_f32 (__builtin_amdgcn_rcpf): R2 lost ~800 cyc/step
//     to precise-division fixup sequences.
//   - bf16x3 split GEMM as R2 (absmax 6.1e-5 known good).
// grid 256 x 256 thr (4 waves, 1 block/CU); wave w owns units [16w,16w+16)
// for all 4 gates of BOTH layers; C-frag: col=lane&15=batch, row=q*4+r=unit.

#define TT 512
#define HH 64
#define NB 16
#define XP 516     // xbuf pitch (floats): stride%32==4 banks -> 2-way only (free)

typedef __bf16 bf16_t;
typedef bf16_t bf16x8 __attribute__((ext_vector_type(8)));
typedef float  f32x4  __attribute__((ext_vector_type(4)));
typedef unsigned short us4 __attribute__((ext_vector_type(4)));

#define MFMA(A, B, C) __builtin_amdgcn_mfma_f32_16x16x32_bf16((A), (B), (C), 0, 0, 0)

__device__ __forceinline__ unsigned short f32_to_bf16_rne(float f) {
    unsigned int u = __builtin_bit_cast(unsigned int, f);
    unsigned int r = u + 0x7fffu + ((u >> 16) & 1u);
    return (unsigned short)(r >> 16);
}
__device__ __forceinline__ float bf16bits_to_f32(unsigned short s) {
    return __builtin_bit_cast(float, ((unsigned int)s) << 16);
}
__device__ __forceinline__ bf16_t bits_to_bf16(unsigned short u) {
    return __builtin_bit_cast(bf16_t, u);
}
// h split: hi RNE, lo RTZ (lo error ~2^-17 rel, negligible; saves 3 instr)
__device__ __forceinline__ void split_h(float f, unsigned short& hi, unsigned short& lo) {
    unsigned int u = __builtin_bit_cast(unsigned int, f);
    unsigned int r = (u + 0x7fffu + ((u >> 16) & 1u)) & 0xffff0000u;
    hi = (unsigned short)(r >> 16);
    float d = f - __builtin_bit_cast(float, r);
    lo = (unsigned short)(__builtin_bit_cast(unsigned int, d) >> 16);
}
// weight split (one-time): both RNE
__device__ __forceinline__ void build_frags(const float* __restrict__ p, bf16x8& hi, bf16x8& lo) {
    const float4 a = *(const float4*)p;
    const float4 b = *(const float4*)(p + 4);
    float v[8] = {a.x, a.y, a.z, a.w, b.x, b.y, b.z, b.w};
#pragma unroll
    for (int j = 0; j < 8; ++j) {
        unsigned short h = f32_to_bf16_rne(v[j]);
        float d = v[j] - bf16bits_to_f32(h);
        hi[j] = bits_to_bf16(h);
        lo[j] = bits_to_bf16(f32_to_bf16_rne(d));
    }
}

#define RCPF(x) __builtin_amdgcn_rcpf(x)
__device__ __forceinline__ float sigm_f(float v) {
    return RCPF(1.0f + __expf(-v));                       // v_mul+v_exp+v_add+v_rcp
}
__device__ __forceinline__ float tanh_f(float v) {
    return fmaf(-2.0f, RCPF(1.0f + __expf(v + v)), 1.0f); // tail-safe both ends
}

__global__ __launch_bounds__(256, 1)
void lstm_pipe_kernel(const float* __restrict__ x,
                      const float* __restrict__ Wih0, const float* __restrict__ Whh0,
                      const float* __restrict__ bih0, const float* __restrict__ bhh0,
                      const float* __restrict__ Wih1, const float* __restrict__ Whh1,
                      const float* __restrict__ bih1, const float* __restrict__ bhh1,
                      const float* __restrict__ Wfc,  const float* __restrict__ bfc,
                      float* __restrict__ out)
{
    __shared__ float xbuf[NB][XP];                   // 33 KB
    // h-state: [parity][row b][16 chunks x 8 shorts]; chunks 0..7 = h0 k,
    // 8..15 = h1 k; physical chunk = (c&8) | ((c&7) ^ (b&7)).
    __shared__ unsigned short ht_hi[2][NB][128];     // 8 KB
    __shared__ unsigned short ht_lo[2][NB][128];     // 8 KB
    __shared__ float h1f[HH][NB + 1];                // 4.25 KB: exact fp32 h1(T-1)

    const int tid  = threadIdx.x;
    const int w    = tid >> 6;
    const int lane = tid & 63;
    const int m    = lane & 15;      // batch col (B/C frag) & A-frag row-in-tile
    const int q    = lane >> 4;
    const int m7   = m & 7;
    const int b0   = blockIdx.x * NB;

    // ---- Stage x (coalesced float4) ----
    for (int i = tid; i < NB * TT / 4; i += 256) {
        const int b  = i >> 7;
        const int t4 = i & 127;
        *(float4*)&xbuf[b][t4 * 4] = *(const float4*)&x[(size_t)(b0 + b) * TT + t4 * 4];
    }
    // ---- zero both parities of h-state ----
    for (int i = tid; i < 2 * NB * 128; i += 256) {
        (&ht_hi[0][0][0])[i] = 0;
        (&ht_lo[0][0][0])[i] = 0;
    }

    // ---- Weight A-fragments (A[m][k]: row=64G+16w+m, k=kt*32+q*8+j) ----
    bf16x8 A0h[4][2], A0l[4][2];     // Whh0 (K=64)
    bf16x8 A1h[4][4], A1l[4][4];     // [Wih1 | Whh1] (K=128): kt 0-1 eat h0, 2-3 eat h1
#pragma unroll
    for (int G = 0; G < 4; ++G) {
        const int row = 64 * G + 16 * w + m;
#pragma unroll
        for (int kt = 0; kt < 2; ++kt)
            build_frags(&Whh0[row * HH + kt * 32 + q * 8], A0h[G][kt], A0l[G][kt]);
#pragma unroll
        for (int kt = 0; kt < 2; ++kt)
            build_frags(&Wih1[row * HH + kt * 32 + q * 8], A1h[G][kt], A1l[G][kt]);
#pragma unroll
        for (int kt = 0; kt < 2; ++kt)
            build_frags(&Whh1[row * HH + kt * 32 + q * 8], A1h[G][2 + kt], A1l[G][2 + kt]);
    }

    // ---- Per-lane bias / Wih0 (C-frag rows: unit u = 16w + q*4 + r) ----
    f32x4 bb0v[4], wxv[4], bb1v[4];
#pragma unroll
    for (int G = 0; G < 4; ++G) {
#pragma unroll
        for (int r = 0; r < 4; ++r) {
            const int row = 64 * G + 16 * w + q * 4 + r;
            bb0v[G][r] = bih0[row] + bhh0[row];
            wxv[G][r]  = Wih0[row];
            bb1v[G][r] = bih1[row] + bhh1[row];
        }
    }

    // ---- Precomputed per-lane LDS short-offsets (within one parity = 2048) ----
    int roff[2][2];                  // [layer][kt] read frag offset
#pragma unroll
    for (int L = 0; L < 2; ++L)
#pragma unroll
        for (int kt = 0; kt < 2; ++kt)
            roff[L][kt] = m * 128 + (((L << 3) | ((4 * kt + q) ^ m7)) * 8);
    const int c0w   = 2 * w + (q >> 1);                 // write chunk (units u0..u0+3)
    const int woff0 = m * 128 + ((c0w ^ m7) * 8) + 4 * (q & 1);          // h0
    const int woff1 = m * 128 + (((8 | (c0w ^ m7))) * 8) + 4 * (q & 1);  // h1

    const int u0 = 16 * w + q * 4;
    f32x4 c0 = {0.f, 0.f, 0.f, 0.f};
    f32x4 c1 = {0.f, 0.f, 0.f, 0.f};

    unsigned short* const Hh = &ht_hi[0][0][0];
    unsigned short* const Hl = &ht_lo[0][0][0];

    __syncthreads();

#pragma unroll 1
    for (int t = 0; t <= TT; ++t) {
        const int rb = ((t + 1) & 1) * 2048;    // read parity (old state)
        const int wb = (t & 1) * 2048;          // write parity (new state)

        // ---- all B-frag reads of old state ----
        bf16x8 h0h[2], h0l[2], h1h[2], h1l[2];
#pragma unroll
        for (int kt = 0; kt < 2; ++kt) {
            h0h[kt] = *(const bf16x8*)(Hh + rb + roff[0][kt]);
            h0l[kt] = *(const bf16x8*)(Hl + rb + roff[0][kt]);
            h1h[kt] = *(const bf16x8*)(Hh + rb + roff[1][kt]);
            h1l[kt] = *(const bf16x8*)(Hl + rb + roff[1][kt]);
        }
        const float xv = xbuf[m][(t < TT) ? t : 0];

        // ---- L0(t) gates: 24 MFMA (runs on edge steps too; update is guarded) ----
        f32x4 a0[4], a1[4];
#pragma unroll
        for (int G = 0; G < 4; ++G) {
#pragma unroll
            for (int r = 0; r < 4; ++r) a0[G][r] = fmaf(xv, wxv[G][r], bb0v[G][r]);
#pragma unroll
            for (int kt = 0; kt < 2; ++kt) {
                a0[G] = MFMA(A0h[G][kt], h0h[kt], a0[G]);
                a0[G] = MFMA(A0h[G][kt], h0l[kt], a0[G]);
                a0[G] = MFMA(A0l[G][kt], h0h[kt], a0[G]);
            }
        }
        // ---- L1(t-1) gates: 48 MFMA (h0(t-1) and h1(t-2) both from old parity) ----
#pragma unroll
        for (int G = 0; G < 4; ++G) {
            a1[G] = bb1v[G];
#pragma unroll
            for (int kt = 0; kt < 2; ++kt) {
                a1[G] = MFMA(A1h[G][kt], h0h[kt], a1[G]);
                a1[G] = MFMA(A1h[G][kt], h0l[kt], a1[G]);
                a1[G] = MFMA(A1l[G][kt], h0h[kt], a1[G]);
            }
#pragma unroll
            for (int kt = 0; kt < 2; ++kt) {
                a1[G] = MFMA(A1h[G][2 + kt], h1h[kt], a1[G]);
                a1[G] = MFMA(A1h[G][2 + kt], h1l[kt], a1[G]);
                a1[G] = MFMA(A1l[G][2 + kt], h1h[kt], a1[G]);
            }
        }

        // ---- L0 update (VALU overlaps L1 MFMA pipe) ----
        if (t < TT) {
            us4 ph, pl;
#pragma unroll
            for (int r = 0; r < 4; ++r) {
                const float ig = sigm_f(a0[0][r]);
                const float fg = sigm_f(a0[1][r]);
                const float gg = tanh_f(a0[2][r]);
                const float og = sigm_f(a0[3][r]);
                const float c  = fmaf(fg, c0[r], ig * gg);
                c0[r] = c;
                const float hv = og * tanh_f(c);
                unsigned short hb, lb;
                split_h(hv, hb, lb);
                ph[r] = hb; pl[r] = lb;
            }
            *(us4*)(Hh + wb + woff0) = ph;
            *(us4*)(Hl + wb + woff0) = pl;
        }
        // ---- L1 update ----
        if (t > 0) {
            us4 ph, pl;
#pragma unroll
            for (int r = 0; r < 4; ++r) {
                const float ig = sigm_f(a1[0][r]);
                const float fg = sigm_f(a1[1][r]);
                const float gg = tanh_f(a1[2][r]);
                const float og = sigm_f(a1[3][r]);
                const float c  = fmaf(fg, c1[r], ig * gg);
                c1[r] = c;
                const float hv = og * tanh_f(c);
                unsigned short hb, lb;
                split_h(hv, hb, lb);
                ph[r] = hb; pl[r] = lb;
                if (t == TT) h1f[u0 + r][m] = hv;     // exact fp32 h1(T-1) for FC
            }
            *(us4*)(Hh + wb + woff1) = ph;
            *(us4*)(Hl + wb + woff1) = pl;
        }
        __syncthreads();    // writes of parity wb visible before next step reads
    }

    // ---- FC epilogue: out[b] = h1(T-1)[b] . Wfc + bfc ----
    if (tid < NB) {
        float s = bfc[0];
#pragma unroll
        for (int u = 0; u < HH; ++u) s = fmaf(h1f[u][tid], Wfc[u], s);
        out[b0 + tid] = s;
    }
}

extern "C" void kernel_launch(void* const* d_in, const int* in_sizes, int n_in,
                              void* d_out, int out_size, void* d_ws, size_t ws_size,
                              hipStream_t stream) {
    const float* x    = (const float*)d_in[0];
    const float* Wih0 = (const float*)d_in[1];
    const float* Whh0 = (const float*)d_in[2];
    const float* bih0 = (const float*)d_in[3];
    const float* bhh0 = (const float*)d_in[4];
    const float* Wih1 = (const float*)d_in[5];
    const float* Whh1 = (const float*)d_in[6];
    const float* bih1 = (const float*)d_in[7];
    const float* bhh1 = (const float*)d_in[8];
    const float* Wfc  = (const float*)d_in[9];
    const float* bfc  = (const float*)d_in[10];

    lstm_pipe_kernel<<<dim3(4096 / NB), dim3(256), 0, stream>>>(
        x, Wih0, Whh0, bih0, bhh0, Wih1, Whh1, bih1, bhh1, Wfc, bfc, (float*)d_out);
}

// Round 5
// 680.885 us; speedup vs baseline: 23.1024x; 1.2226x over previous
//
#include <hip/hip_runtime.h>

// LSTMForecaster: B=4096, T=512, D=1, H=64, 2 layers + FC(64->1).
// R5 (= R4 with compile fix): wave-specialized 2-waves/SIMD kernel.
//   R3 post-mortem: 1 block/CU = 1 wave/SIMD -> MFMA (31%) and VALU (51%) pipes
//   can't overlap across waves; step = near-sum of pipes + 18% drain.
//   Fix: 512-thr blocks (8 waves), grid 256. Waves 0-3 compute L0(t) (24 MFMA),
//   waves 4-7 compute L1(t-1) (48 MFMA); w and w+4 share a SIMD -> per-SIMD
//   72 MFMA/step from 2 independent streams, VALU of one hides MFMA of other.
//   Two separate t-loops (one per wave class) keep A-frag live ranges disjoint
//   (L0: 64 VGPR, L1: 128 VGPR); s_barrier counts align (513 each).
//   + shared-rcp gate algebra (8 trans/cell vs 10), RTZ h-split.
//   bf16x3 split GEMM unchanged (absmax 6.1e-5 known good).
//   R4 compile fix: c-state as float[4] (vector elements can't bind to float&).

#define TT 512
#define HH 64
#define NB 16
#define XP 516

typedef __bf16 bf16_t;
typedef bf16_t bf16x8 __attribute__((ext_vector_type(8)));
typedef float  f32x4  __attribute__((ext_vector_type(4)));
typedef unsigned short us4 __attribute__((ext_vector_type(4)));

#define MFMA(A, B, C) __builtin_amdgcn_mfma_f32_16x16x32_bf16((A), (B), (C), 0, 0, 0)
#define RCPF(x) __builtin_amdgcn_rcpf(x)

__device__ __forceinline__ unsigned short f32_to_bf16_rne(float f) {
    unsigned int u = __builtin_bit_cast(unsigned int, f);
    unsigned int r = u + 0x7fffu + ((u >> 16) & 1u);
    return (unsigned short)(r >> 16);
}
__device__ __forceinline__ float bf16bits_to_f32(unsigned short s) {
    return __builtin_bit_cast(float, ((unsigned int)s) << 16);
}
__device__ __forceinline__ bf16_t bits_to_bf16(unsigned short u) {
    return __builtin_bit_cast(bf16_t, u);
}
// h split: hi RTZ (lo captures the residual exactly; combined err ~2^-16 rel)
__device__ __forceinline__ void split_h(float f, unsigned short& hi, unsigned short& lo) {
    unsigned int u = __builtin_bit_cast(unsigned int, f);
    hi = (unsigned short)(u >> 16);
    float d = f - __builtin_bit_cast(float, u & 0xffff0000u);
    lo = (unsigned short)(__builtin_bit_cast(unsigned int, d) >> 16);
}
// weight split (one-time): both RNE
__device__ __forceinline__ void build_frags(const float* __restrict__ p, bf16x8& hi, bf16x8& lo) {
    const float4 a = *(const float4*)p;
    const float4 b = *(const float4*)(p + 4);
    float v[8] = {a.x, a.y, a.z, a.w, b.x, b.y, b.z, b.w};
#pragma unroll
    for (int j = 0; j < 8; ++j) {
        unsigned short h = f32_to_bf16_rne(v[j]);
        float d = v[j] - bf16bits_to_f32(h);
        hi[j] = bits_to_bf16(h);
        lo[j] = bits_to_bf16(f32_to_bf16_rne(d));
    }
}

// Full cell: returns h, updates c (by pointer). Shared-rcp algebra:
//   sigm(i)*tanh(g) = (e^{2g}-1) / ((1+e^{-i})(1+e^{2g}))   [1 rcp]
//   sigm(o)*tanh(c) = (e^{2c}-1) / ((1+e^{-o})(1+e^{2c}))   [1 rcp]
// Range-safe: |preact| <~ 17, |c| <~ 5 for this weight/input scale.
__device__ __forceinline__ float lstm_cell(float gi, float gf, float gg, float go, float* c) {
    const float pf = __expf(-gf);
    const float fg = RCPF(1.0f + pf);
    const float pi = __expf(-gi);
    const float e2 = __expf(gg + gg);
    const float z  = (e2 - 1.0f) * RCPF((1.0f + pi) * (1.0f + e2));
    *c = fmaf(fg, *c, z);
    const float po  = __expf(-go);
    const float e2c = __expf(*c + *c);
    return (e2c - 1.0f) * RCPF((1.0f + po) * (1.0f + e2c));
}

__global__ __launch_bounds__(512, 2)
void lstm_ws_kernel(const float* __restrict__ x,
                    const float* __restrict__ Wih0, const float* __restrict__ Whh0,
                    const float* __restrict__ bih0, const float* __restrict__ bhh0,
                    const float* __restrict__ Wih1, const float* __restrict__ Whh1,
                    const float* __restrict__ bih1, const float* __restrict__ bhh1,
                    const float* __restrict__ Wfc,  const float* __restrict__ bfc,
                    float* __restrict__ out)
{
    __shared__ float xbuf[NB][XP];                   // 33 KB
    // h-state: [parity][b][16 chunks x 8 shorts]; chunks 0..7 h0, 8..15 h1;
    // physical chunk = (c&8) | ((c&7) ^ (b&7)).
    __shared__ unsigned short ht_hi[2][NB][128];     // 8 KB
    __shared__ unsigned short ht_lo[2][NB][128];     // 8 KB
    __shared__ float h1f[HH][NB + 1];                // 4.25 KB

    const int tid  = threadIdx.x;
    const int wv   = tid >> 6;       // 0..7; 0-3 = L0 waves, 4-7 = L1 waves
    const int lane = tid & 63;
    const int m    = lane & 15;      // batch col / A-row-in-tile
    const int q    = lane >> 4;
    const int m7   = m & 7;
    const int b0   = blockIdx.x * NB;
    const int w    = wv & 3;         // unit-tile index within layer

    // ---- Stage x (coalesced float4) ----
    for (int i = tid; i < NB * TT / 4; i += 512) {
        const int b  = i >> 7;
        const int t4 = i & 127;
        *(float4*)&xbuf[b][t4 * 4] = *(const float4*)&x[(size_t)(b0 + b) * TT + t4 * 4];
    }
    // ---- zero both parities ----
    for (int i = tid; i < 2 * NB * 128; i += 512) {
        (&ht_hi[0][0][0])[i] = 0;
        (&ht_lo[0][0][0])[i] = 0;
    }

    // ---- per-lane read offsets (shorts, within one parity block of 2048) ----
    int roff[2][2];
#pragma unroll
    for (int L = 0; L < 2; ++L)
#pragma unroll
        for (int kt = 0; kt < 2; ++kt)
            roff[L][kt] = m * 128 + (((L << 3) | ((4 * kt + q) ^ m7)) * 8);
    const int cw    = 2 * w + (q >> 1);
    const int woff0 = m * 128 + ((cw ^ m7) * 8) + 4 * (q & 1);          // h0 write
    const int woff1 = m * 128 + ((8 | (cw ^ m7)) * 8) + 4 * (q & 1);    // h1 write
    const int u0    = 16 * w + q * 4;

    unsigned short* const Hh = &ht_hi[0][0][0];
    unsigned short* const Hl = &ht_lo[0][0][0];

    __syncthreads();

    if (wv < 4) {
        // ================= L0 waves: compute h0(t), 24 MFMA/step =================
        bf16x8 A0h[4][2], A0l[4][2];
        f32x4 bb0[4], wx0[4];
#pragma unroll
        for (int G = 0; G < 4; ++G) {
            const int rowA = 64 * G + 16 * w + m;
#pragma unroll
            for (int kt = 0; kt < 2; ++kt)
                build_frags(&Whh0[rowA * HH + kt * 32 + q * 8], A0h[G][kt], A0l[G][kt]);
#pragma unroll
            for (int r = 0; r < 4; ++r) {
                const int row = 64 * G + 16 * w + q * 4 + r;
                bb0[G][r] = bih0[row] + bhh0[row];
                wx0[G][r] = Wih0[row];
            }
        }

        float c0[4] = {0.f, 0.f, 0.f, 0.f};

#pragma unroll 1
        for (int t = 0; t <= TT; ++t) {
            if (t < TT) {
                const int rb = ((t + 1) & 1) * 2048;
                const int wb = (t & 1) * 2048;
                bf16x8 h0h[2], h0l[2];
#pragma unroll
                for (int kt = 0; kt < 2; ++kt) {
                    h0h[kt] = *(const bf16x8*)(Hh + rb + roff[0][kt]);
                    h0l[kt] = *(const bf16x8*)(Hl + rb + roff[0][kt]);
                }
                const float xv = xbuf[m][t];

                f32x4 a0[4];
#pragma unroll
                for (int G = 0; G < 4; ++G) {
#pragma unroll
                    for (int r = 0; r < 4; ++r) a0[G][r] = fmaf(xv, wx0[G][r], bb0[G][r]);
#pragma unroll
                    for (int kt = 0; kt < 2; ++kt) {
                        a0[G] = MFMA(A0h[G][kt], h0h[kt], a0[G]);
                        a0[G] = MFMA(A0h[G][kt], h0l[kt], a0[G]);
                        a0[G] = MFMA(A0l[G][kt], h0h[kt], a0[G]);
                    }
                }
                us4 ph, pl;
#pragma unroll
                for (int r = 0; r < 4; ++r) {
                    const float hv = lstm_cell(a0[0][r], a0[1][r], a0[2][r], a0[3][r], &c0[r]);
                    unsigned short hb, lb;
                    split_h(hv, hb, lb);
                    ph[r] = hb; pl[r] = lb;
                }
                *(us4*)(Hh + wb + woff0) = ph;
                *(us4*)(Hl + wb + woff0) = pl;
            }
            __syncthreads();
        }
    } else {
        // ============== L1 waves: compute h1(t-1), 48 MFMA/step ==============
        bf16x8 A1h[4][4], A1l[4][4];    // kt 0-1: Wih1 (eats h0), kt 2-3: Whh1 (eats h1)
        f32x4 bb1[4];
#pragma unroll
        for (int G = 0; G < 4; ++G) {
            const int rowA = 64 * G + 16 * w + m;
#pragma unroll
            for (int kt = 0; kt < 2; ++kt)
                build_frags(&Wih1[rowA * HH + kt * 32 + q * 8], A1h[G][kt], A1l[G][kt]);
#pragma unroll
            for (int kt = 0; kt < 2; ++kt)
                build_frags(&Whh1[rowA * HH + kt * 32 + q * 8], A1h[G][2 + kt], A1l[G][2 + kt]);
#pragma unroll
            for (int r = 0; r < 4; ++r) {
                const int row = 64 * G + 16 * w + q * 4 + r;
                bb1[G][r] = bih1[row] + bhh1[row];
            }
        }

        float c1[4] = {0.f, 0.f, 0.f, 0.f};

#pragma unroll 1
        for (int t = 0; t <= TT; ++t) {
            if (t > 0) {
                const int rb = ((t + 1) & 1) * 2048;
                const int wb = (t & 1) * 2048;
                bf16x8 h0h[2], h0l[2], h1h[2], h1l[2];
#pragma unroll
                for (int kt = 0; kt < 2; ++kt) {
                    h0h[kt] = *(const bf16x8*)(Hh + rb + roff[0][kt]);
                    h0l[kt] = *(const bf16x8*)(Hl + rb + roff[0][kt]);
                    h1h[kt] = *(const bf16x8*)(Hh + rb + roff[1][kt]);
                    h1l[kt] = *(const bf16x8*)(Hl + rb + roff[1][kt]);
                }

                f32x4 a1[4];
#pragma unroll
                for (int G = 0; G < 4; ++G) {
                    a1[G] = bb1[G];
#pragma unroll
                    for (int kt = 0; kt < 2; ++kt) {
                        a1[G] = MFMA(A1h[G][kt], h0h[kt], a1[G]);
                        a1[G] = MFMA(A1h[G][kt], h0l[kt], a1[G]);
                        a1[G] = MFMA(A1l[G][kt], h0h[kt], a1[G]);
                    }
#pragma unroll
                    for (int kt = 0; kt < 2; ++kt) {
                        a1[G] = MFMA(A1h[G][2 + kt], h1h[kt], a1[G]);
                        a1[G] = MFMA(A1h[G][2 + kt], h1l[kt], a1[G]);
                        a1[G] = MFMA(A1l[G][2 + kt], h1h[kt], a1[G]);
                    }
                }
                us4 ph, pl;
#pragma unroll
                for (int r = 0; r < 4; ++r) {
                    const float hv = lstm_cell(a1[0][r], a1[1][r], a1[2][r], a1[3][r], &c1[r]);
                    unsigned short hb, lb;
                    split_h(hv, hb, lb);
                    ph[r] = hb; pl[r] = lb;
                    if (t == TT) h1f[u0 + r][m] = hv;    // exact fp32 h1(T-1) for FC
                }
                *(us4*)(Hh + wb + woff1) = ph;
                *(us4*)(Hl + wb + woff1) = pl;
            }
            __syncthreads();
        }
    }

    // ---- FC epilogue: out[b] = h1(T-1)[b] . Wfc + bfc ----
    if (tid < NB) {
        float s = bfc[0];
#pragma unroll
        for (int u = 0; u < HH; ++u) s = fmaf(h1f[u][tid], Wfc[u], s);
        out[b0 + tid] = s;
    }
}

extern "C" void kernel_launch(void* const* d_in, const int* in_sizes, int n_in,
                              void* d_out, int out_size, void* d_ws, size_t ws_size,
                              hipStream_t stream) {
    const float* x    = (const float*)d_in[0];
    const float* Wih0 = (const float*)d_in[1];
    const float* Whh0 = (const float*)d_in[2];
    const float* bih0 = (const float*)d_in[3];
    const float* bhh0 = (const float*)d_in[4];
    const float* Wih1 = (const float*)d_in[5];
    const float* Whh1 = (const float*)d_in[6];
    const float* bih1 = (const float*)d_in[7];
    const float* bhh1 = (const float*)d_in[8];
    const float* Wfc  = (const float*)d_in[9];
    const float* bfc  = (const float*)d_in[10];

    lstm_ws_kernel<<<dim3(4096 / NB), dim3(512), 0, stream>>>(
        x, Wih0, Whh0, bih0, bhh0, Wih1, Whh1, bih1, bhh1, Wfc, bfc, (float*)d_out);
}

// Round 6
// 612.493 us; speedup vs baseline: 25.6820x; 1.1117x over previous
//
#include <hip/hip_runtime.h>

// LSTMForecaster: B=4096, T=512, D=1, H=64, 2 layers + FC(64->1).
// R6: 4-waves/SIMD via M-split. 1024-thr blocks (16 waves), grid 256, NB=16.
//   R5 post-mortem: 2 waves/SIMD -> MFMA 38% + VALU 52%, step 2x the perfect-
//   overlap bound; intra-wave dep chains exposed. Fix: 8 L0 waves (8 units ea)
//   + 8 L1 waves (8 units ea); per SIMD 2 L0 + 2 L1 = 72 MFMA from 4 streams.
//   Unit-major row permutation inside each 16-row tile (row = 4*unit + gate):
//   C-frag reg index = gate, quad = unit -> cell update register-local at
//   8 units/wave. Gate scales (-log2e / +2log2e) folded into weight frags ->
//   activations are raw v_exp_f32 (exp2), no preprocessing ops.
//   __launch_bounds__(1024,4): 128 VGPR cap (4 waves/SIMD). Spill watch:
//   FETCH_SIZE must stay ~5 MB.
//   bf16x3 split GEMM + shared-rcp cell unchanged (absmax 6.1e-5 known good).

#define TT 512
#define HH 64
#define NB 16
#define XP 516

typedef __bf16 bf16_t;
typedef bf16_t bf16x8 __attribute__((ext_vector_type(8)));
typedef float  f32x4  __attribute__((ext_vector_type(4)));

#define MFMA(A, B, C) __builtin_amdgcn_mfma_f32_16x16x32_bf16((A), (B), (C), 0, 0, 0)
#define RCPF(x) __builtin_amdgcn_rcpf(x)

#if __has_builtin(__builtin_amdgcn_exp2f)
#define EXP2F(x) __builtin_amdgcn_exp2f(x)
#else
__device__ __forceinline__ float EXP2F(float x) {
    float r;
    asm volatile("v_exp_f32 %0, %1" : "=v"(r) : "v"(x));
    return r;
}
#endif

#define SC_IFO (-1.4426950408889634f)   // -log2(e)
#define SC_G   ( 2.8853900817779268f)   // +2*log2(e)

__device__ __forceinline__ unsigned short f32_to_bf16_rne(float f) {
    unsigned int u = __builtin_bit_cast(unsigned int, f);
    unsigned int r = u + 0x7fffu + ((u >> 16) & 1u);
    return (unsigned short)(r >> 16);
}
__device__ __forceinline__ float bf16bits_to_f32(unsigned short s) {
    return __builtin_bit_cast(float, ((unsigned int)s) << 16);
}
__device__ __forceinline__ bf16_t bits_to_bf16(unsigned short u) {
    return __builtin_bit_cast(bf16_t, u);
}
// h split: hi RTZ, lo = exact residual rounded RTZ (combined err ~2^-16 rel)
__device__ __forceinline__ void split_h(float f, unsigned short& hi, unsigned short& lo) {
    unsigned int u = __builtin_bit_cast(unsigned int, f);
    hi = (unsigned short)(u >> 16);
    float d = f - __builtin_bit_cast(float, u & 0xffff0000u);
    lo = (unsigned short)(__builtin_bit_cast(unsigned int, d) >> 16);
}
// weight split with per-row scale folded in (one-time)
__device__ __forceinline__ void build_frags_scaled(const float* __restrict__ p, float sc,
                                                   bf16x8& hi, bf16x8& lo) {
    const float4 a = *(const float4*)p;
    const float4 b = *(const float4*)(p + 4);
    float v[8] = {a.x, a.y, a.z, a.w, b.x, b.y, b.z, b.w};
#pragma unroll
    for (int j = 0; j < 8; ++j) {
        const float s = v[j] * sc;
        unsigned short h = f32_to_bf16_rne(s);
        float d = s - bf16bits_to_f32(h);
        hi[j] = bits_to_bf16(h);
        lo[j] = bits_to_bf16(f32_to_bf16_rne(d));
    }
}

// Cell on PRE-SCALED gates: is_=-log2e*i, fs_=-log2e*f, gs_=2log2e*g, os_=-log2e*o.
//   sigm(i)*tanh(g) = (e2-1) / ((1+pi)(1+e2)),  e2 = exp2(gs_), pi = exp2(is_)
// Range-safe: |preact| <~ 10 here -> exp2 args <~ 29, products < 1e13.
__device__ __forceinline__ float lstm_cell(float is_, float fs_, float gs_, float os_, float* c) {
    const float pf = EXP2F(fs_);
    const float fg = RCPF(1.0f + pf);
    const float pi = EXP2F(is_);
    const float e2 = EXP2F(gs_);
    const float z  = (e2 - 1.0f) * RCPF((1.0f + pi) * (1.0f + e2));
    *c = fmaf(fg, *c, z);
    const float po  = EXP2F(os_);
    const float e2c = EXP2F(*c * SC_G);
    return (e2c - 1.0f) * RCPF((1.0f + po) * (1.0f + e2c));
}

__global__ __launch_bounds__(1024, 4)
void lstm_ws16_kernel(const float* __restrict__ x,
                      const float* __restrict__ Wih0, const float* __restrict__ Whh0,
                      const float* __restrict__ bih0, const float* __restrict__ bhh0,
                      const float* __restrict__ Wih1, const float* __restrict__ Whh1,
                      const float* __restrict__ bih1, const float* __restrict__ bhh1,
                      const float* __restrict__ Wfc,  const float* __restrict__ bfc,
                      float* __restrict__ out)
{
    __shared__ float xbuf[NB][XP];                   // 33 KB
    // h-state: [parity][b][16 chunks x 8 shorts]; chunks 0..7 h0, 8..15 h1;
    // physical chunk = (c&8) | ((c&7) ^ (b&7)).
    __shared__ unsigned short ht_hi[2][NB][128];     // 8 KB
    __shared__ unsigned short ht_lo[2][NB][128];     // 8 KB
    __shared__ float h1f[HH][NB + 1];                // 4.25 KB

    const int tid  = threadIdx.x;
    const int wv   = tid >> 6;       // 0..15; 0-7 = L0 waves, 8-15 = L1 waves
    const int lane = tid & 63;
    const int m    = lane & 15;      // batch col (B/C) & A-frag row-in-tile
    const int q    = lane >> 4;
    const int m7   = m & 7;
    const int b0   = blockIdx.x * NB;
    const bool isL0 = (wv < 8);
    const int j    = isL0 ? wv : (wv - 8);   // unit-group: units [8j, 8j+8)

    // ---- Stage x (coalesced float4) ----
    for (int i = tid; i < NB * TT / 4; i += 1024) {
        const int b  = i >> 7;
        const int t4 = i & 127;
        *(float4*)&xbuf[b][t4 * 4] = *(const float4*)&x[(size_t)(b0 + b) * TT + t4 * 4];
    }
    // ---- zero both parities ----
    for (int i = tid; i < 2 * NB * 128; i += 1024) {
        (&ht_hi[0][0][0])[i] = 0;
        (&ht_lo[0][0][0])[i] = 0;
    }

    // ---- per-lane read offsets (shorts, within one parity block of 2048) ----
    int roff[2][2];
#pragma unroll
    for (int L = 0; L < 2; ++L)
#pragma unroll
        for (int kt = 0; kt < 2; ++kt)
            roff[L][kt] = m * 128 + (((L << 3) | ((4 * kt + q) ^ m7)) * 8);
    // write base: lane's units u = 8j + 4*tau + q -> chunk j, offset 4*tau+q
    const int wchunk0 = m * 128 + ((j ^ m7) * 8) + q;          // L0, tau=0 (+4 for tau=1)
    const int wchunk1 = m * 128 + ((8 | (j ^ m7)) * 8) + q;    // L1

    // A-frag row for lane (unit-major tile): gate = m&3, unit_local = m>>2
    const int gate_m  = m & 3;
    const float scA   = (gate_m == 2) ? SC_G : SC_IFO;
    unsigned short* const Hh = &ht_hi[0][0][0];
    unsigned short* const Hl = &ht_lo[0][0][0];

    __syncthreads();

    if (isL0) {
        // ======== L0 waves: h0(t) for units [8j,8j+8), 12 MFMA/step ========
        bf16x8 A0h[2][2], A0l[2][2];     // [tau][kt], K=64 of Whh0
        f32x4 bb0s[2], wx0s[2];          // per-tau, reg=gate (scaled)
#pragma unroll
        for (int tau = 0; tau < 2; ++tau) {
            const int rowA = 64 * gate_m + (8 * j + 4 * tau + (m >> 2));
#pragma unroll
            for (int kt = 0; kt < 2; ++kt)
                build_frags_scaled(&Whh0[rowA * HH + kt * 32 + q * 8], scA,
                                   A0h[tau][kt], A0l[tau][kt]);
#pragma unroll
            for (int r = 0; r < 4; ++r) {
                const int row = 64 * r + (8 * j + 4 * tau + q);
                const float sc = (r == 2) ? SC_G : SC_IFO;
                bb0s[tau][r] = (bih0[row] + bhh0[row]) * sc;
                wx0s[tau][r] = Wih0[row] * sc;
            }
        }

        float c0[2] = {0.f, 0.f};

#pragma unroll 1
        for (int t = 0; t <= TT; ++t) {
            if (t < TT) {
                const int rb = ((t + 1) & 1) * 2048;
                const int wb = (t & 1) * 2048;
                const float xv = xbuf[m][t];
                f32x4 a[2];
#pragma unroll
                for (int tau = 0; tau < 2; ++tau)
#pragma unroll
                    for (int r = 0; r < 4; ++r)
                        a[tau][r] = fmaf(xv, wx0s[tau][r], bb0s[tau][r]);
#pragma unroll
                for (int kt = 0; kt < 2; ++kt) {
                    const bf16x8 bh = *(const bf16x8*)(Hh + rb + roff[0][kt]);
                    const bf16x8 bl = *(const bf16x8*)(Hl + rb + roff[0][kt]);
#pragma unroll
                    for (int tau = 0; tau < 2; ++tau) {
                        a[tau] = MFMA(A0h[tau][kt], bh, a[tau]);
                        a[tau] = MFMA(A0h[tau][kt], bl, a[tau]);
                        a[tau] = MFMA(A0l[tau][kt], bh, a[tau]);
                    }
                }
#pragma unroll
                for (int tau = 0; tau < 2; ++tau) {
                    const float hv = lstm_cell(a[tau][0], a[tau][1], a[tau][2], a[tau][3], &c0[tau]);
                    unsigned short hb, lb;
                    split_h(hv, hb, lb);
                    Hh[wb + wchunk0 + 4 * tau] = hb;
                    Hl[wb + wchunk0 + 4 * tau] = lb;
                }
            }
            __syncthreads();
        }
    } else {
        // ======== L1 waves: h1(t-1) for units [8j,8j+8), 24 MFMA/step ========
        bf16x8 A1h[2][4], A1l[2][4];     // [tau][kt]: kt 0-1 Wih1 (eats h0), 2-3 Whh1 (eats h1)
        f32x4 bb1s[2];
#pragma unroll
        for (int tau = 0; tau < 2; ++tau) {
            const int rowA = 64 * gate_m + (8 * j + 4 * tau + (m >> 2));
#pragma unroll
            for (int kt = 0; kt < 2; ++kt)
                build_frags_scaled(&Wih1[rowA * HH + kt * 32 + q * 8], scA,
                                   A1h[tau][kt], A1l[tau][kt]);
#pragma unroll
            for (int kt = 0; kt < 2; ++kt)
                build_frags_scaled(&Whh1[rowA * HH + kt * 32 + q * 8], scA,
                                   A1h[tau][2 + kt], A1l[tau][2 + kt]);
#pragma unroll
            for (int r = 0; r < 4; ++r) {
                const int row = 64 * r + (8 * j + 4 * tau + q);
                const float sc = (r == 2) ? SC_G : SC_IFO;
                bb1s[tau][r] = (bih1[row] + bhh1[row]) * sc;
            }
        }

        float c1[2] = {0.f, 0.f};

#pragma unroll 1
        for (int t = 0; t <= TT; ++t) {
            if (t > 0) {
                const int rb = ((t + 1) & 1) * 2048;
                const int wb = (t & 1) * 2048;
                f32x4 a[2];
                a[0] = bb1s[0];
                a[1] = bb1s[1];
#pragma unroll
                for (int kt = 0; kt < 2; ++kt) {       // eats h0(t-1)
                    const bf16x8 bh = *(const bf16x8*)(Hh + rb + roff[0][kt]);
                    const bf16x8 bl = *(const bf16x8*)(Hl + rb + roff[0][kt]);
#pragma unroll
                    for (int tau = 0; tau < 2; ++tau) {
                        a[tau] = MFMA(A1h[tau][kt], bh, a[tau]);
                        a[tau] = MFMA(A1h[tau][kt], bl, a[tau]);
                        a[tau] = MFMA(A1l[tau][kt], bh, a[tau]);
                    }
                }
#pragma unroll
                for (int kt = 0; kt < 2; ++kt) {       // eats h1(t-2)
                    const bf16x8 bh = *(const bf16x8*)(Hh + rb + roff[1][kt]);
                    const bf16x8 bl = *(const bf16x8*)(Hl + rb + roff[1][kt]);
#pragma unroll
                    for (int tau = 0; tau < 2; ++tau) {
                        a[tau] = MFMA(A1h[tau][2 + kt], bh, a[tau]);
                        a[tau] = MFMA(A1h[tau][2 + kt], bl, a[tau]);
                        a[tau] = MFMA(A1l[tau][2 + kt], bh, a[tau]);
                    }
                }
#pragma unroll
                for (int tau = 0; tau < 2; ++tau) {
                    const float hv = lstm_cell(a[tau][0], a[tau][1], a[tau][2], a[tau][3], &c1[tau]);
                    unsigned short hb, lb;
                    split_h(hv, hb, lb);
                    Hh[wb + wchunk1 + 4 * tau] = hb;
                    Hl[wb + wchunk1 + 4 * tau] = lb;
                    if (t == TT) h1f[8 * j + 4 * tau + q][m] = hv;   // exact fp32 for FC
                }
            }
            __syncthreads();
        }
    }

    // ---- FC epilogue: out[b] = h1(T-1)[b] . Wfc + bfc ----
    if (tid < NB) {
        float s = bfc[0];
#pragma unroll
        for (int u = 0; u < HH; ++u) s = fmaf(h1f[u][tid], Wfc[u], s);
        out[b0 + tid] = s;
    }
}

extern "C" void kernel_launch(void* const* d_in, const int* in_sizes, int n_in,
                              void* d_out, int out_size, void* d_ws, size_t ws_size,
                              hipStream_t stream) {
    const float* x    = (const float*)d_in[0];
    const float* Wih0 = (const float*)d_in[1];
    const float* Whh0 = (const float*)d_in[2];
    const float* bih0 = (const float*)d_in[3];
    const float* bhh0 = (const float*)d_in[4];
    const float* Wih1 = (const float*)d_in[5];
    const float* Whh1 = (const float*)d_in[6];
    const float* bih1 = (const float*)d_in[7];
    const float* bhh1 = (const float*)d_in[8];
    const float* Wfc  = (const float*)d_in[9];
    const float* bfc  = (const float*)d_in[10];

    lstm_ws16_kernel<<<dim3(4096 / NB), dim3(1024), 0, stream>>>(
        x, Wih0, Whh0, bih0, bhh0, Wih1, Whh1, bih1, bhh1, Wfc, bfc, (float*)d_out);
}